// Round 10
// baseline (96.087 us; speedup 1.0000x reference)
//
#include <hip/hip_runtime.h>
#include <hip/hip_bf16.h>

typedef _Float16 half8 __attribute__((ext_vector_type(8)));
typedef float    floatx4 __attribute__((ext_vector_type(4)));

#define WSCALE      4096.0f
#define WSCALE_INV  (1.0f/(4096.0f*4096.0f))

// ws layout (float offsets)
#define T1_OFF   0      // 4096 floats (16,16,16)
#define U_OFF    4096   // 4096 floats (16,4,4,4,4)
#define WF16_OFF 8192   // 65536 _Float16, fragment-major; 16B-aligned

// ---- Prep 1 (validated R9): TWO INDEPENDENT register-tiled blocks ----
__global__ __launch_bounds__(256)
void mpo_prep1(const float* __restrict__ w, float* __restrict__ ws) {
    __shared__ __align__(16) float wL[3136];
    __shared__ __align__(16) float sL[4352];
    const int tid = threadIdx.x;

    {
        const floatx4* s4 = reinterpret_cast<const floatx4*>(w + blockIdx.x * 3136);
        floatx4* d4 = reinterpret_cast<floatx4*>(wL);
        for (int i = tid; i < 784; i += 256) d4[i] = s4[i];
    }
    __syncthreads();

    if (blockIdx.x == 0) {
        {
            int li = tid;
            int mm = li & 3, kk = (li >> 2) & 3, c = li >> 4;
            int k1 = kk >> 1, k2 = kk & 1, m1 = mm >> 1, m2 = mm & 1;
            float s = 0.f;
#pragma unroll
            for (int b = 0; b < 16; ++b)
                s += wL[b * 4 + k1 * 2 + m1] * wL[64 + b * 64 + c * 4 + k2 * 2 + m2];
            sL[li] = s;
        }
        {
            const int i0 = (tid >> 4) * 4, j0 = (tid & 15) * 4;
            const float* Ab = wL + 1088 + (i0 >> 2) * 64;
            const float* Bb = wL + 2112 + j0;
            float acc[4][4] = {};
#pragma unroll
            for (int b = 0; b < 16; ++b) {
                floatx4 ar = *reinterpret_cast<const floatx4*>(Ab + b * 4);
                floatx4 br = *reinterpret_cast<const floatx4*>(Bb + b * 64);
#pragma unroll
                for (int r = 0; r < 4; ++r)
#pragma unroll
                    for (int s = 0; s < 4; ++s) acc[r][s] += ar[r] * br[s];
            }
#pragma unroll
            for (int r = 0; r < 4; ++r)
#pragma unroll
            for (int s = 0; s < 4; ++s) {
                int i = i0 + r, j = j0 + s;
                sL[256 + (i >> 2) * 256 + (j >> 2) * 16 +
                   ((i >> 1) & 1) * 8 + ((j >> 1) & 1) * 4 + (i & 1) * 2 + (j & 1)] = acc[r][s];
            }
        }
        __syncthreads();
        {
            const int p0 = (tid >> 6) * 4, q0 = (tid & 63) * 4;
            float acc[4][4] = {};
#pragma unroll
            for (int a = 0; a < 16; ++a) {
                floatx4 pr = *reinterpret_cast<const floatx4*>(sL + a * 16 + p0);
                floatx4 qr = *reinterpret_cast<const floatx4*>(sL + 256 + a * 256 + q0);
#pragma unroll
                for (int r = 0; r < 4; ++r)
#pragma unroll
                    for (int s = 0; s < 4; ++s) acc[r][s] += pr[r] * qr[s];
            }
#pragma unroll
            for (int r = 0; r < 4; ++r)
#pragma unroll
            for (int s = 0; s < 4; ++s) {
                int p = p0 + r, q = q0 + s;
                ws[T1_OFF + (q >> 4) * 256 + ((p >> 2) * 4 + ((q >> 2) & 3)) * 16 +
                   (p & 3) * 4 + (q & 3)] = acc[r][s];
            }
        }
    } else {
        {
            const int i0 = (tid >> 4) * 4, j0 = (tid & 15) * 4;
            const float* Ab = wL + (i0 >> 2) * 64;
            const float* Bb = wL + 1024 + j0;
            float acc[4][4] = {};
#pragma unroll
            for (int b = 0; b < 16; ++b) {
                floatx4 ar = *reinterpret_cast<const floatx4*>(Ab + b * 4);
                floatx4 br = *reinterpret_cast<const floatx4*>(Bb + b * 64);
#pragma unroll
                for (int r = 0; r < 4; ++r)
#pragma unroll
                    for (int s = 0; s < 4; ++s) acc[r][s] += ar[r] * br[s];
            }
#pragma unroll
            for (int r = 0; r < 4; ++r)
#pragma unroll
            for (int s = 0; s < 4; ++s) {
                int i = i0 + r, j = j0 + s;
                sL[(i >> 2) * 256 + (j >> 2) * 16 +
                   ((i >> 1) & 1) * 8 + ((j >> 1) & 1) * 4 + (i & 1) * 2 + (j & 1)] = acc[r][s];
            }
        }
        {
            int li = tid;
            int mm = li & 3, kk = (li >> 2) & 3, a = li >> 4;
            int k1 = kk >> 1, k2 = kk & 1, m1 = mm >> 1, m2 = mm & 1;
            float s = 0.f;
#pragma unroll
            for (int b = 0; b < 16; ++b)
                s += wL[2048 + a * 64 + b * 4 + k1 * 2 + m1] * wL[3072 + b * 4 + k2 * 2 + m2];
            sL[4096 + li] = s;
        }
        __syncthreads();
        {
            const int r0 = (tid >> 2) * 4, q0 = (tid & 3) * 4;
            float acc[4][4] = {};
#pragma unroll
            for (int b = 0; b < 16; ++b) {
                floatx4 ar = *reinterpret_cast<const floatx4*>(sL + (r0 >> 4) * 256 + b * 16 + (r0 & 15));
                floatx4 br = *reinterpret_cast<const floatx4*>(sL + 4096 + b * 16 + q0);
#pragma unroll
                for (int r = 0; r < 4; ++r)
#pragma unroll
                    for (int s = 0; s < 4; ++s) acc[r][s] += ar[r] * br[s];
            }
#pragma unroll
            for (int r = 0; r < 4; ++r)
#pragma unroll
            for (int s = 0; s < 4; ++s)
                ws[U_OFF + (r0 + r) * 16 + q0 + s] = acc[r][s];
        }
    }
}

// ---- Prep 2 (validated): W from T1 x U, fp16, fragment-major ----
__global__ __launch_bounds__(256)
void mpo_prep2(const float* __restrict__ ws, _Float16* __restrict__ Wf) {
    int idx = blockIdx.x * blockDim.x + threadIdx.x;   // 65536
    int J4 = idx & 255, I4 = idx >> 8;                 // col, k
    int I16 = I4 >> 4, kc = (I4 >> 2) & 3, k2 = I4 & 3;
    int J16 = J4 >> 4, mc = (J4 >> 2) & 3, m2 = J4 & 3;
    const float* T1 = ws + T1_OFF;
    const float* U  = ws + U_OFF + (((kc * 4 + mc) * 4 + k2) * 4 + m2);
    float s = 0.f;
#pragma unroll
    for (int a = 0; a < 16; ++a)
        s += T1[(a * 16 + I16) * 16 + J16] * U[a * 256];
    int n = J4 >> 4, lr = J4 & 15, kk = I4 >> 5, gg = (I4 >> 3) & 3, j = I4 & 7;
    Wf[(((n * 8 + kk) * 64) + gg * 16 + lr) * 8 + j] = (_Float16)(s * WSCALE);
}

// ---- Main fused kernel: W-IN-REGISTERS, x-SHARED-VIA-LDS(fp16) ----
// 256 blocks x 512 threads (8 waves). Each wave owns 2 column-strips of W
// in registers (64 VGPR, loaded once from L2). Per pass (128 rows): each
// wave prefetches its 16 rows (1-deep cross-pass, validated), converts to
// fp16, ds_writes 8 KB; every wave then reads all 8 rowtiles from LDS
// (64 KB/wave vs 128 KB/wave of the old W-broadcast -> LDS off critical
// path). Cross-wave col-reduction via 4 KB LDS partials. 2 barriers/pass.
__global__ __launch_bounds__(512, 2)
void mpo_main(const float* __restrict__ x, const _Float16* __restrict__ Wf,
              const float* __restrict__ dk, const float* __restrict__ bias,
              float* __restrict__ out) {
    extern __shared__ __align__(16) char smem[];
    half8* xL = reinterpret_cast<half8*>(smem);            // 4096 half8 = 64 KB
    float* pL = reinterpret_cast<float*>(smem + 65536);    // 1024 floats = 4 KB

    const int tid  = threadIdx.x;
    const int lane = tid & 63;
    const int wave = tid >> 6;        // 0..7 (= rowtile it stages, = strip-pair it owns)
    const int lrow = lane & 15;
    const int g    = lane >> 4;

    const long blockbase = (long)blockIdx.x * 1024;
    const float* xb0 = x + (blockbase + wave * 16 + lrow) * 256 + g * 8;

    half8 a[8];
    floatx4 lo[8], hi[8];

#define SB()  __builtin_amdgcn_sched_barrier(0)
#define NTL(p) __builtin_nontemporal_load(reinterpret_cast<const floatx4*>(p))
#define XLD(i, xn) do { const float* p_ = (xn) + (i) * 32; lo[i] = NTL(p_); hi[i] = NTL(p_ + 4); } while (0)
#define XLD_ALL(xn) do { XLD(0,xn); XLD(1,xn); XLD(2,xn); XLD(3,xn); \
                         XLD(4,xn); XLD(5,xn); XLD(6,xn); XLD(7,xn); } while (0)
#define XCVT(i) do { half8 f_;                                                \
                     f_[0] = (_Float16)lo[i][0]; f_[1] = (_Float16)lo[i][1];  \
                     f_[2] = (_Float16)lo[i][2]; f_[3] = (_Float16)lo[i][3];  \
                     f_[4] = (_Float16)hi[i][0]; f_[5] = (_Float16)hi[i][1];  \
                     f_[6] = (_Float16)hi[i][2]; f_[7] = (_Float16)hi[i][3];  \
                     a[i] = f_; } while (0)
#define XCVT_ALL() do { XCVT(0); XCVT(1); XCVT(2); XCVT(3); \
                        XCVT(4); XCVT(5); XCVT(6); XCVT(7); } while (0)
#define XSTORE_ALL() do { _Pragma("unroll") \
    for (int kk = 0; kk < 8; ++kk) xL[(wave * 8 + kk) * 64 + lane] = a[kk]; } while (0)

    // ---- prologue: start x(0) HBM stream, then W-frags (L2) + dk + bias ----
    XLD_ALL(xb0);
    SB();
    half8 Wr0[8], Wr1[8];
    {
        const half8* Wg = reinterpret_cast<const half8*>(Wf);
#pragma unroll
        for (int kk = 0; kk < 8; ++kk) {
            Wr0[kk] = Wg[((wave * 2) * 8 + kk) * 64 + lane];
            Wr1[kk] = Wg[((wave * 2 + 1) * 8 + kk) * 64 + lane];
        }
    }
    const float kv0 = dk[wave * 32 + lrow];
    const float kv1 = dk[wave * 32 + 16 + lrow];
    const float bs  = bias[0];
    XCVT_ALL();
    XSTORE_ALL();
    __syncthreads();   // B1(0): x(0) staged

#pragma unroll 1
    for (int p = 0; p < 8; ++p) {
        // issue next pass's x loads; they stream during compute
        if (p < 7) { XLD_ALL(xb0 + (p + 1) * (128 * 256)); }
        SB();

#pragma unroll 1
        for (int t = 0; t < 8; ++t) {
            half8 at[8];
#pragma unroll
            for (int kk = 0; kk < 8; ++kk) at[kk] = xL[(t * 8 + kk) * 64 + lane];
            floatx4 c0 = {0, 0, 0, 0}, c1 = {0, 0, 0, 0};
#pragma unroll
            for (int kk = 0; kk < 8; ++kk) {
                c0 = __builtin_amdgcn_mfma_f32_16x16x32_f16(at[kk], Wr0[kk], c0, 0, 0, 0);
                c1 = __builtin_amdgcn_mfma_f32_16x16x32_f16(at[kk], Wr1[kk], c1, 0, 0, 0);
            }
            floatx4 rp;
#pragma unroll
            for (int r = 0; r < 4; ++r)
                rp[r] = c0[r] * c0[r] * kv0 + c1[r] * c1[r] * kv1;
#pragma unroll
            for (int r = 0; r < 4; ++r) {
                float v = rp[r];
                v += __shfl_xor(v, 1);
                v += __shfl_xor(v, 2);
                v += __shfl_xor(v, 4);
                v += __shfl_xor(v, 8);
                rp[r] = v;
            }
            if (lrow == 0)
                *reinterpret_cast<floatx4*>(pL + ((t * 4 + g) * 8 + wave) * 4) = rp;
        }
        __syncthreads();   // B2: partials complete, x(p) reads complete

        // final cross-wave reduce + store (rows = tid 0..127)
        if (tid < 128) {
            float s = 0.f;
#pragma unroll
            for (int w2 = 0; w2 < 8; ++w2)
                s += pL[((tid >> 2) * 8 + w2) * 4 + (tid & 3)];
            out[blockbase + p * 128 + tid] = s * WSCALE_INV + bs;
        }

        // stage next pass's x (xL safe to overwrite: after B2)
        if (p < 7) {
            XCVT_ALL();
            XSTORE_ALL();
        }
        __syncthreads();   // B1(p+1): x staged / pL reduce done before next writes
    }
}

extern "C" void kernel_launch(void* const* d_in, const int* in_sizes, int n_in,
                              void* d_out, int out_size, void* d_ws, size_t ws_size,
                              hipStream_t stream) {
    const float* x    = (const float*)d_in[0];
    const float* w    = (const float*)d_in[1];
    const float* dk   = (const float*)d_in[2];
    const float* bias = (const float*)d_in[3];
    float* out = (float*)d_out;
    float* ws  = (float*)d_ws;

    _Float16* Wf16 = (_Float16*)(ws + WF16_OFF);

    // Allow 68 KB dynamic LDS for mpo_main (host-side attr; pattern R5-R9).
    static bool attr_set = false;
    if (!attr_set) {
        hipFuncSetAttribute((const void*)mpo_main,
                            hipFuncAttributeMaxDynamicSharedMemorySize, 69632);
        attr_set = true;
    }

    // W contraction: prep1 (2 register-tiled blocks), then prep2
    mpo_prep1<<<2, 256, 0, stream>>>(w, ws);
    mpo_prep2<<<256, 256, 0, stream>>>(ws, Wf16);

    // Main fused GEMM + square + dot: 256 blocks x 512 threads, 68 KB LDS
    mpo_main<<<256, 512, 69632, stream>>>(x, Wf16, dk, bias, out);
}

// Round 11
// 69.490 us; speedup vs baseline: 1.3827x; 1.3827x over previous
//
#include <hip/hip_runtime.h>
#include <hip/hip_bf16.h>

typedef _Float16 half8 __attribute__((ext_vector_type(8)));
typedef float    floatx4 __attribute__((ext_vector_type(4)));

#define WSCALE      4096.0f
#define WSCALE_INV  (1.0f/(4096.0f*4096.0f))

// ws layout (float offsets)
#define T1_OFF   0      // 4096 floats (16,16,16)
#define U_OFF    4096   // 4096 floats (16,4,4,4,4)
#define WF16_OFF 8192   // 65536 _Float16, fragment-major; 16B-aligned

// ---- Prep 1 (validated R9 algebra): TWO INDEPENDENT register-tiled blocks ----
__global__ __launch_bounds__(256)
void mpo_prep1(const float* __restrict__ w, float* __restrict__ ws) {
    __shared__ __align__(16) float wL[3136];
    __shared__ __align__(16) float sL[4352];
    const int tid = threadIdx.x;

    {
        const floatx4* s4 = reinterpret_cast<const floatx4*>(w + blockIdx.x * 3136);
        floatx4* d4 = reinterpret_cast<floatx4*>(wL);
        for (int i = tid; i < 784; i += 256) d4[i] = s4[i];
    }
    __syncthreads();

    if (blockIdx.x == 0) {
        {
            int li = tid;
            int mm = li & 3, kk = (li >> 2) & 3, c = li >> 4;
            int k1 = kk >> 1, k2 = kk & 1, m1 = mm >> 1, m2 = mm & 1;
            float s = 0.f;
#pragma unroll
            for (int b = 0; b < 16; ++b)
                s += wL[b * 4 + k1 * 2 + m1] * wL[64 + b * 64 + c * 4 + k2 * 2 + m2];
            sL[li] = s;
        }
        {
            const int i0 = (tid >> 4) * 4, j0 = (tid & 15) * 4;
            const float* Ab = wL + 1088 + (i0 >> 2) * 64;
            const float* Bb = wL + 2112 + j0;
            float acc[4][4] = {};
#pragma unroll
            for (int b = 0; b < 16; ++b) {
                floatx4 ar = *reinterpret_cast<const floatx4*>(Ab + b * 4);
                floatx4 br = *reinterpret_cast<const floatx4*>(Bb + b * 64);
#pragma unroll
                for (int r = 0; r < 4; ++r)
#pragma unroll
                    for (int s = 0; s < 4; ++s) acc[r][s] += ar[r] * br[s];
            }
#pragma unroll
            for (int r = 0; r < 4; ++r)
#pragma unroll
            for (int s = 0; s < 4; ++s) {
                int i = i0 + r, j = j0 + s;
                sL[256 + (i >> 2) * 256 + (j >> 2) * 16 +
                   ((i >> 1) & 1) * 8 + ((j >> 1) & 1) * 4 + (i & 1) * 2 + (j & 1)] = acc[r][s];
            }
        }
        __syncthreads();
        {
            const int p0 = (tid >> 6) * 4, q0 = (tid & 63) * 4;
            float acc[4][4] = {};
#pragma unroll
            for (int a = 0; a < 16; ++a) {
                floatx4 pr = *reinterpret_cast<const floatx4*>(sL + a * 16 + p0);
                floatx4 qr = *reinterpret_cast<const floatx4*>(sL + 256 + a * 256 + q0);
#pragma unroll
                for (int r = 0; r < 4; ++r)
#pragma unroll
                    for (int s = 0; s < 4; ++s) acc[r][s] += pr[r] * qr[s];
            }
#pragma unroll
            for (int r = 0; r < 4; ++r)
#pragma unroll
            for (int s = 0; s < 4; ++s) {
                int p = p0 + r, q = q0 + s;
                ws[T1_OFF + (q >> 4) * 256 + ((p >> 2) * 4 + ((q >> 2) & 3)) * 16 +
                   (p & 3) * 4 + (q & 3)] = acc[r][s];
            }
        }
    } else {
        {
            const int i0 = (tid >> 4) * 4, j0 = (tid & 15) * 4;
            const float* Ab = wL + (i0 >> 2) * 64;
            const float* Bb = wL + 1024 + j0;
            float acc[4][4] = {};
#pragma unroll
            for (int b = 0; b < 16; ++b) {
                floatx4 ar = *reinterpret_cast<const floatx4*>(Ab + b * 4);
                floatx4 br = *reinterpret_cast<const floatx4*>(Bb + b * 64);
#pragma unroll
                for (int r = 0; r < 4; ++r)
#pragma unroll
                    for (int s = 0; s < 4; ++s) acc[r][s] += ar[r] * br[s];
            }
#pragma unroll
            for (int r = 0; r < 4; ++r)
#pragma unroll
            for (int s = 0; s < 4; ++s) {
                int i = i0 + r, j = j0 + s;
                sL[(i >> 2) * 256 + (j >> 2) * 16 +
                   ((i >> 1) & 1) * 8 + ((j >> 1) & 1) * 4 + (i & 1) * 2 + (j & 1)] = acc[r][s];
            }
        }
        {
            int li = tid;
            int mm = li & 3, kk = (li >> 2) & 3, a = li >> 4;
            int k1 = kk >> 1, k2 = kk & 1, m1 = mm >> 1, m2 = mm & 1;
            float s = 0.f;
#pragma unroll
            for (int b = 0; b < 16; ++b)
                s += wL[2048 + a * 64 + b * 4 + k1 * 2 + m1] * wL[3072 + b * 4 + k2 * 2 + m2];
            sL[4096 + li] = s;
        }
        __syncthreads();
        {
            const int r0 = (tid >> 2) * 4, q0 = (tid & 3) * 4;
            float acc[4][4] = {};
#pragma unroll
            for (int b = 0; b < 16; ++b) {
                floatx4 ar = *reinterpret_cast<const floatx4*>(sL + (r0 >> 4) * 256 + b * 16 + (r0 & 15));
                floatx4 br = *reinterpret_cast<const floatx4*>(sL + 4096 + b * 16 + q0);
#pragma unroll
                for (int r = 0; r < 4; ++r)
#pragma unroll
                    for (int s = 0; s < 4; ++s) acc[r][s] += ar[r] * br[s];
            }
#pragma unroll
            for (int r = 0; r < 4; ++r)
#pragma unroll
            for (int s = 0; s < 4; ++s)
                ws[U_OFF + (r0 + r) * 16 + q0 + s] = acc[r][s];
        }
    }
}

// ---- Prep 2 (validated): W from T1 x U, fp16, fragment-major ----
__global__ __launch_bounds__(256)
void mpo_prep2(const float* __restrict__ ws, _Float16* __restrict__ Wf) {
    int idx = blockIdx.x * blockDim.x + threadIdx.x;   // 65536
    int J4 = idx & 255, I4 = idx >> 8;                 // col, k
    int I16 = I4 >> 4, kc = (I4 >> 2) & 3, k2 = I4 & 3;
    int J16 = J4 >> 4, mc = (J4 >> 2) & 3, m2 = J4 & 3;
    const float* T1 = ws + T1_OFF;
    const float* U  = ws + U_OFF + (((kc * 4 + mc) * 4 + k2) * 4 + m2);
    float s = 0.f;
#pragma unroll
    for (int a = 0; a < 16; ++a)
        s += T1[(a * 16 + I16) * 16 + J16] * U[a * 256];
    int n = J4 >> 4, lr = J4 & 15, kk = I4 >> 5, gg = (I4 >> 3) & 3, j = I4 & 7;
    Wf[(((n * 8 + kk) * 64) + gg * 16 + lr) * 8 + j] = (_Float16)(s * WSCALE);
}

// ---- Main fused kernel: R7/R8 validated structure + 32 ROWS/WAVE ----
// 256 blocks x 512 threads, W (128 KB) + dk in LDS, ONE barrier, no per-pass
// barriers (waves de-phase freely). Each wave owns 32 rows per pass (2 row
// sets sharing every B fragment -> LDS B-read traffic HALVED vs R8: ~22 us,
// off the critical path; HBM 41.6 us is now the sole limit). 4 passes.
// Register discipline (R3/R9 lessons): single lo/hi[8] prefetch buffer,
// unroll-1 n-loop, no duplicated code paths. ~190 VGPR < 256 cap.
__global__ __launch_bounds__(512, 2)
void mpo_main(const float* __restrict__ x, const _Float16* __restrict__ Wf,
              const float* __restrict__ dk, const float* __restrict__ bias,
              float* __restrict__ out) {
    extern __shared__ _Float16 Wl[];                       // 65536 halves + 256 floats
    float* dkL = reinterpret_cast<float*>(Wl + 65536);

    const int tid  = threadIdx.x;
    const int lane = tid & 63;
    const int wave = tid >> 6;        // 0..7
    const int lrow = lane & 15;
    const int g    = lane >> 4;

    const long blockbase = (long)blockIdx.x * 1024;
    // wave's rows for pass p, set s: blockbase + p*256 + wave*32 + s*16 + lrow
    const float* xb = x + (blockbase + wave * 32 + lrow) * 256 + g * 8;
    const int PASS_STRIDE = 256 * 256;   // floats per pass (256 rows)
    const int SET_STRIDE  = 16 * 256;    // floats per row-set

    half8 a0[8], a1[8];
    floatx4 lo[8], hi[8];

#define SB()  __builtin_amdgcn_sched_barrier(0)
#define NTL(p) __builtin_nontemporal_load(reinterpret_cast<const floatx4*>(p))
#define XLD(i, xn) do { const float* p_ = (xn) + (i) * 32; lo[i] = NTL(p_); hi[i] = NTL(p_ + 4); } while (0)
#define XLD_ALL(xn) do { XLD(0,xn); XLD(1,xn); XLD(2,xn); XLD(3,xn); \
                         XLD(4,xn); XLD(5,xn); XLD(6,xn); XLD(7,xn); } while (0)
#define XCVT(dst, i) do { half8 f_;                                           \
                     f_[0] = (_Float16)lo[i][0]; f_[1] = (_Float16)lo[i][1];  \
                     f_[2] = (_Float16)lo[i][2]; f_[3] = (_Float16)lo[i][3];  \
                     f_[4] = (_Float16)hi[i][0]; f_[5] = (_Float16)hi[i][1];  \
                     f_[6] = (_Float16)hi[i][2]; f_[7] = (_Float16)hi[i][3];  \
                     dst[i] = f_; } while (0)
#define XCVT_ALL(dst) do { XCVT(dst,0); XCVT(dst,1); XCVT(dst,2); XCVT(dst,3); \
                           XCVT(dst,4); XCVT(dst,5); XCVT(dst,6); XCVT(dst,7); } while (0)

    // ---- prologue: issue x(0,set0); stage W+dk; sync; cvt set0; set1 ----
    XLD_ALL(xb);
    SB();
    {
        const floatx4* src = reinterpret_cast<const floatx4*>(Wf);
        floatx4* dst = reinterpret_cast<floatx4*>(Wl);
#pragma unroll
        for (int i = 0; i < 16; ++i)
            dst[tid + i * 512] = src[tid + i * 512];
    }
    if (tid < 256) dkL[tid] = dk[tid];
    const float bs = bias[0];
    __syncthreads();   // the only barrier
    XCVT_ALL(a0);
    XLD_ALL(xb + SET_STRIDE);
    SB();
    XCVT_ALL(a1);
    SB();

    const half8* Wv = reinterpret_cast<const half8*>(Wl);

#pragma unroll 1
    for (int p = 0; p < 4; ++p) {
        // issue next pass set0; streams during the n-loop
        if (p < 3) { XLD_ALL(xb + (p + 1) * PASS_STRIDE); }
        SB();

        float rp0[4] = {0, 0, 0, 0}, rp1[4] = {0, 0, 0, 0};
#pragma unroll 1
        for (int n = 0; n < 16; ++n) {
            const float kv = dkL[n * 16 + lrow];           // LDS: no vmcnt wait
            const half8* Wn = Wv + n * 512 + lane;
            floatx4 c0 = {0, 0, 0, 0}, c1 = {0, 0, 0, 0};
#pragma unroll
            for (int kk = 0; kk < 8; ++kk) {
                half8 b = Wn[kk * 64];
                c0 = __builtin_amdgcn_mfma_f32_16x16x32_f16(a0[kk], b, c0, 0, 0, 0);
                c1 = __builtin_amdgcn_mfma_f32_16x16x32_f16(a1[kk], b, c1, 0, 0, 0);
            }
#pragma unroll
            for (int r = 0; r < 4; ++r) {
                rp0[r] += c0[r] * c0[r] * kv;
                rp1[r] += c1[r] * c1[r] * kv;
            }
        }

        // reduce over the 16 cols (lanes sharing g) and store both row-sets
#pragma unroll
        for (int r = 0; r < 4; ++r) {
            float v0 = rp0[r], v1 = rp1[r];
            v0 += __shfl_xor(v0, 1); v1 += __shfl_xor(v1, 1);
            v0 += __shfl_xor(v0, 2); v1 += __shfl_xor(v1, 2);
            v0 += __shfl_xor(v0, 4); v1 += __shfl_xor(v1, 4);
            v0 += __shfl_xor(v0, 8); v1 += __shfl_xor(v1, 8);
            rp0[r] = v0; rp1[r] = v1;
        }
        if (lrow == 0) {
            floatx4 o0, o1;
#pragma unroll
            for (int r = 0; r < 4; ++r) {
                o0[r] = rp0[r] * WSCALE_INV + bs;
                o1[r] = rp1[r] * WSCALE_INV + bs;
            }
            float* ob = out + blockbase + p * 256 + wave * 32 + g * 4;
            *reinterpret_cast<floatx4*>(ob)      = o0;
            *reinterpret_cast<floatx4*>(ob + 16) = o1;
        }

        // convert set0 (loads long complete), then issue+convert set1
        if (p < 3) {
            XCVT_ALL(a0);
            XLD_ALL(xb + (p + 1) * PASS_STRIDE + SET_STRIDE);
            SB();
            XCVT_ALL(a1);
        }
        SB();
    }
}

extern "C" void kernel_launch(void* const* d_in, const int* in_sizes, int n_in,
                              void* d_out, int out_size, void* d_ws, size_t ws_size,
                              hipStream_t stream) {
    const float* x    = (const float*)d_in[0];
    const float* w    = (const float*)d_in[1];
    const float* dk   = (const float*)d_in[2];
    const float* bias = (const float*)d_in[3];
    float* out = (float*)d_out;
    float* ws  = (float*)d_ws;

    _Float16* Wf16 = (_Float16*)(ws + WF16_OFF);

    // Allow 129 KB dynamic LDS for mpo_main (host-side attr; validated R5-R9).
    static bool attr_set = false;
    if (!attr_set) {
        hipFuncSetAttribute((const void*)mpo_main,
                            hipFuncAttributeMaxDynamicSharedMemorySize, 132096);
        attr_set = true;
    }

    // W contraction: prep1 (2 register-tiled blocks), then prep2
    mpo_prep1<<<2, 256, 0, stream>>>(w, ws);
    mpo_prep2<<<256, 256, 0, stream>>>(ws, Wf16);

    // Main fused GEMM + square + dot: 256 blocks x 512 threads, 129 KB LDS
    mpo_main<<<256, 512, 132096, stream>>>(x, Wf16, dk, bias, out);
}

// Round 12
// 63.781 us; speedup vs baseline: 1.5065x; 1.0895x over previous
//
#include <hip/hip_runtime.h>
#include <hip/hip_bf16.h>

typedef _Float16 half8 __attribute__((ext_vector_type(8)));
typedef float    floatx4 __attribute__((ext_vector_type(4)));

#define WSCALE      4096.0f
#define WSCALE_INV  (1.0f/(4096.0f*4096.0f))

// ws layout (float offsets)
#define T1_OFF   0      // 4096 floats (16,16,16)
#define U_OFF    4096   // 4096 floats (16,4,4,4,4)
#define WF16_OFF 8192   // 65536 _Float16, fragment-major; 16B-aligned

// ---- Prep 1 (validated R9 algebra): TWO INDEPENDENT register-tiled blocks ----
__global__ __launch_bounds__(256)
void mpo_prep1(const float* __restrict__ w, float* __restrict__ ws) {
    __shared__ __align__(16) float wL[3136];
    __shared__ __align__(16) float sL[4352];
    const int tid = threadIdx.x;

    {
        const floatx4* s4 = reinterpret_cast<const floatx4*>(w + blockIdx.x * 3136);
        floatx4* d4 = reinterpret_cast<floatx4*>(wL);
        for (int i = tid; i < 784; i += 256) d4[i] = s4[i];
    }
    __syncthreads();

    if (blockIdx.x == 0) {
        {
            int li = tid;
            int mm = li & 3, kk = (li >> 2) & 3, c = li >> 4;
            int k1 = kk >> 1, k2 = kk & 1, m1 = mm >> 1, m2 = mm & 1;
            float s = 0.f;
#pragma unroll
            for (int b = 0; b < 16; ++b)
                s += wL[b * 4 + k1 * 2 + m1] * wL[64 + b * 64 + c * 4 + k2 * 2 + m2];
            sL[li] = s;
        }
        {
            const int i0 = (tid >> 4) * 4, j0 = (tid & 15) * 4;
            const float* Ab = wL + 1088 + (i0 >> 2) * 64;
            const float* Bb = wL + 2112 + j0;
            float acc[4][4] = {};
#pragma unroll
            for (int b = 0; b < 16; ++b) {
                floatx4 ar = *reinterpret_cast<const floatx4*>(Ab + b * 4);
                floatx4 br = *reinterpret_cast<const floatx4*>(Bb + b * 64);
#pragma unroll
                for (int r = 0; r < 4; ++r)
#pragma unroll
                    for (int s = 0; s < 4; ++s) acc[r][s] += ar[r] * br[s];
            }
#pragma unroll
            for (int r = 0; r < 4; ++r)
#pragma unroll
            for (int s = 0; s < 4; ++s) {
                int i = i0 + r, j = j0 + s;
                sL[256 + (i >> 2) * 256 + (j >> 2) * 16 +
                   ((i >> 1) & 1) * 8 + ((j >> 1) & 1) * 4 + (i & 1) * 2 + (j & 1)] = acc[r][s];
            }
        }
        __syncthreads();
        {
            const int p0 = (tid >> 6) * 4, q0 = (tid & 63) * 4;
            float acc[4][4] = {};
#pragma unroll
            for (int a = 0; a < 16; ++a) {
                floatx4 pr = *reinterpret_cast<const floatx4*>(sL + a * 16 + p0);
                floatx4 qr = *reinterpret_cast<const floatx4*>(sL + 256 + a * 256 + q0);
#pragma unroll
                for (int r = 0; r < 4; ++r)
#pragma unroll
                    for (int s = 0; s < 4; ++s) acc[r][s] += pr[r] * qr[s];
            }
#pragma unroll
            for (int r = 0; r < 4; ++r)
#pragma unroll
            for (int s = 0; s < 4; ++s) {
                int p = p0 + r, q = q0 + s;
                ws[T1_OFF + (q >> 4) * 256 + ((p >> 2) * 4 + ((q >> 2) & 3)) * 16 +
                   (p & 3) * 4 + (q & 3)] = acc[r][s];
            }
        }
    } else {
        {
            const int i0 = (tid >> 4) * 4, j0 = (tid & 15) * 4;
            const float* Ab = wL + (i0 >> 2) * 64;
            const float* Bb = wL + 1024 + j0;
            float acc[4][4] = {};
#pragma unroll
            for (int b = 0; b < 16; ++b) {
                floatx4 ar = *reinterpret_cast<const floatx4*>(Ab + b * 4);
                floatx4 br = *reinterpret_cast<const floatx4*>(Bb + b * 64);
#pragma unroll
                for (int r = 0; r < 4; ++r)
#pragma unroll
                    for (int s = 0; s < 4; ++s) acc[r][s] += ar[r] * br[s];
            }
#pragma unroll
            for (int r = 0; r < 4; ++r)
#pragma unroll
            for (int s = 0; s < 4; ++s) {
                int i = i0 + r, j = j0 + s;
                sL[(i >> 2) * 256 + (j >> 2) * 16 +
                   ((i >> 1) & 1) * 8 + ((j >> 1) & 1) * 4 + (i & 1) * 2 + (j & 1)] = acc[r][s];
            }
        }
        {
            int li = tid;
            int mm = li & 3, kk = (li >> 2) & 3, a = li >> 4;
            int k1 = kk >> 1, k2 = kk & 1, m1 = mm >> 1, m2 = mm & 1;
            float s = 0.f;
#pragma unroll
            for (int b = 0; b < 16; ++b)
                s += wL[2048 + a * 64 + b * 4 + k1 * 2 + m1] * wL[3072 + b * 4 + k2 * 2 + m2];
            sL[4096 + li] = s;
        }
        __syncthreads();
        {
            const int r0 = (tid >> 2) * 4, q0 = (tid & 3) * 4;
            float acc[4][4] = {};
#pragma unroll
            for (int b = 0; b < 16; ++b) {
                floatx4 ar = *reinterpret_cast<const floatx4*>(sL + (r0 >> 4) * 256 + b * 16 + (r0 & 15));
                floatx4 br = *reinterpret_cast<const floatx4*>(sL + 4096 + b * 16 + q0);
#pragma unroll
                for (int r = 0; r < 4; ++r)
#pragma unroll
                    for (int s = 0; s < 4; ++s) acc[r][s] += ar[r] * br[s];
            }
#pragma unroll
            for (int r = 0; r < 4; ++r)
#pragma unroll
            for (int s = 0; s < 4; ++s)
                ws[U_OFF + (r0 + r) * 16 + q0 + s] = acc[r][s];
        }
    }
}

// ---- Prep 2 (validated): W from T1 x U, fp16, fragment-major ----
__global__ __launch_bounds__(256)
void mpo_prep2(const float* __restrict__ ws, _Float16* __restrict__ Wf) {
    int idx = blockIdx.x * blockDim.x + threadIdx.x;   // 65536
    int J4 = idx & 255, I4 = idx >> 8;                 // col, k
    int I16 = I4 >> 4, kc = (I4 >> 2) & 3, k2 = I4 & 3;
    int J16 = J4 >> 4, mc = (J4 >> 2) & 3, m2 = J4 & 3;
    const float* T1 = ws + T1_OFF;
    const float* U  = ws + U_OFF + (((kc * 4 + mc) * 4 + k2) * 4 + m2);
    float s = 0.f;
#pragma unroll
    for (int a = 0; a < 16; ++a)
        s += T1[(a * 16 + I16) * 16 + J16] * U[a * 256];
    int n = J4 >> 4, lr = J4 & 15, kk = I4 >> 5, gg = (I4 >> 3) & 3, j = I4 & 7;
    Wf[(((n * 8 + kk) * 64) + gg * 16 + lr) * 8 + j] = (_Float16)(s * WSCALE);
}

// ---- Main fused kernel: R11 structure, PLAIN x loads (NT removed — A/B),
// and set1-next loads issued before the reduce so the shuffle chain covers
// part of their latency. 32 rows/wave, 4 passes, W+dk in LDS, one barrier.
__global__ __launch_bounds__(512, 2)
void mpo_main(const float* __restrict__ x, const _Float16* __restrict__ Wf,
              const float* __restrict__ dk, const float* __restrict__ bias,
              float* __restrict__ out) {
    extern __shared__ _Float16 Wl[];                       // 65536 halves + 256 floats
    float* dkL = reinterpret_cast<float*>(Wl + 65536);

    const int tid  = threadIdx.x;
    const int lane = tid & 63;
    const int wave = tid >> 6;        // 0..7
    const int lrow = lane & 15;
    const int g    = lane >> 4;

    const long blockbase = (long)blockIdx.x * 1024;
    const float* xb = x + (blockbase + wave * 32 + lrow) * 256 + g * 8;
    const int PASS_STRIDE = 256 * 256;   // floats per pass (256 rows)
    const int SET_STRIDE  = 16 * 256;    // floats per row-set

    half8 a0[8], a1[8];
    floatx4 lo[8], hi[8];

#define SB()  __builtin_amdgcn_sched_barrier(0)
#define XLD(i, xn) do { const float* p_ = (xn) + (i) * 32;              \
                     lo[i] = *reinterpret_cast<const floatx4*>(p_);     \
                     hi[i] = *reinterpret_cast<const floatx4*>(p_ + 4); } while (0)
#define XLD_ALL(xn) do { XLD(0,xn); XLD(1,xn); XLD(2,xn); XLD(3,xn); \
                         XLD(4,xn); XLD(5,xn); XLD(6,xn); XLD(7,xn); } while (0)
#define XCVT(dst, i) do { half8 f_;                                           \
                     f_[0] = (_Float16)lo[i][0]; f_[1] = (_Float16)lo[i][1];  \
                     f_[2] = (_Float16)lo[i][2]; f_[3] = (_Float16)lo[i][3];  \
                     f_[4] = (_Float16)hi[i][0]; f_[5] = (_Float16)hi[i][1];  \
                     f_[6] = (_Float16)hi[i][2]; f_[7] = (_Float16)hi[i][3];  \
                     dst[i] = f_; } while (0)
#define XCVT_ALL(dst) do { XCVT(dst,0); XCVT(dst,1); XCVT(dst,2); XCVT(dst,3); \
                           XCVT(dst,4); XCVT(dst,5); XCVT(dst,6); XCVT(dst,7); } while (0)

    // ---- prologue: issue x(0,set0); stage W+dk; sync; cvt set0; set1 ----
    XLD_ALL(xb);
    SB();
    {
        const floatx4* src = reinterpret_cast<const floatx4*>(Wf);
        floatx4* dst = reinterpret_cast<floatx4*>(Wl);
#pragma unroll
        for (int i = 0; i < 16; ++i)
            dst[tid + i * 512] = src[tid + i * 512];
    }
    if (tid < 256) dkL[tid] = dk[tid];
    const float bs = bias[0];
    __syncthreads();   // the only barrier
    XCVT_ALL(a0);
    XLD_ALL(xb + SET_STRIDE);
    SB();
    XCVT_ALL(a1);
    SB();

    const half8* Wv = reinterpret_cast<const half8*>(Wl);

#pragma unroll 1
    for (int p = 0; p < 4; ++p) {
        // issue next pass set0; streams during the n-loop
        if (p < 3) { XLD_ALL(xb + (p + 1) * PASS_STRIDE); }
        SB();

        float rp0[4] = {0, 0, 0, 0}, rp1[4] = {0, 0, 0, 0};
#pragma unroll 1
        for (int n = 0; n < 16; ++n) {
            const float kv = dkL[n * 16 + lrow];           // LDS: no vmcnt wait
            const half8* Wn = Wv + n * 512 + lane;
            floatx4 c0 = {0, 0, 0, 0}, c1 = {0, 0, 0, 0};
#pragma unroll
            for (int kk = 0; kk < 8; ++kk) {
                half8 b = Wn[kk * 64];
                c0 = __builtin_amdgcn_mfma_f32_16x16x32_f16(a0[kk], b, c0, 0, 0, 0);
                c1 = __builtin_amdgcn_mfma_f32_16x16x32_f16(a1[kk], b, c1, 0, 0, 0);
            }
#pragma unroll
            for (int r = 0; r < 4; ++r) {
                rp0[r] += c0[r] * c0[r] * kv;
                rp1[r] += c1[r] * c1[r] * kv;
            }
        }

        // convert set0-next (loads long complete), issue set1-next EARLY so
        // the reduce below covers part of its latency
        if (p < 3) {
            XCVT_ALL(a0);
            XLD_ALL(xb + (p + 1) * PASS_STRIDE + SET_STRIDE);
        }
        SB();

        // reduce over the 16 cols (lanes sharing g) and store both row-sets
#pragma unroll
        for (int r = 0; r < 4; ++r) {
            float v0 = rp0[r], v1 = rp1[r];
            v0 += __shfl_xor(v0, 1); v1 += __shfl_xor(v1, 1);
            v0 += __shfl_xor(v0, 2); v1 += __shfl_xor(v1, 2);
            v0 += __shfl_xor(v0, 4); v1 += __shfl_xor(v1, 4);
            v0 += __shfl_xor(v0, 8); v1 += __shfl_xor(v1, 8);
            rp0[r] = v0; rp1[r] = v1;
        }
        if (lrow == 0) {
            floatx4 o0, o1;
#pragma unroll
            for (int r = 0; r < 4; ++r) {
                o0[r] = rp0[r] * WSCALE_INV + bs;
                o1[r] = rp1[r] * WSCALE_INV + bs;
            }
            float* ob = out + blockbase + p * 256 + wave * 32 + g * 4;
            *reinterpret_cast<floatx4*>(ob)      = o0;
            *reinterpret_cast<floatx4*>(ob + 16) = o1;
        }

        // convert set1-next (reduce covered part of the latency)
        if (p < 3) { XCVT_ALL(a1); }
        SB();
    }
}

extern "C" void kernel_launch(void* const* d_in, const int* in_sizes, int n_in,
                              void* d_out, int out_size, void* d_ws, size_t ws_size,
                              hipStream_t stream) {
    const float* x    = (const float*)d_in[0];
    const float* w    = (const float*)d_in[1];
    const float* dk   = (const float*)d_in[2];
    const float* bias = (const float*)d_in[3];
    float* out = (float*)d_out;
    float* ws  = (float*)d_ws;

    _Float16* Wf16 = (_Float16*)(ws + WF16_OFF);

    // Allow 129 KB dynamic LDS for mpo_main (host-side attr; validated R5-R11).
    static bool attr_set = false;
    if (!attr_set) {
        hipFuncSetAttribute((const void*)mpo_main,
                            hipFuncAttributeMaxDynamicSharedMemorySize, 132096);
        attr_set = true;
    }

    // W contraction: prep1 (2 register-tiled blocks), then prep2
    mpo_prep1<<<2, 256, 0, stream>>>(w, ws);
    mpo_prep2<<<256, 256, 0, stream>>>(ws, Wf16);

    // Main fused GEMM + square + dot: 256 blocks x 512 threads, 129 KB LDS
    mpo_main<<<256, 512, 132096, stream>>>(x, Wf16, dk, bias, out);
}

// Round 13
// 62.602 us; speedup vs baseline: 1.5349x; 1.0188x over previous
//
#include <hip/hip_runtime.h>
#include <hip/hip_bf16.h>

typedef _Float16 half8 __attribute__((ext_vector_type(8)));
typedef float    floatx4 __attribute__((ext_vector_type(4)));

#define WSCALE      4096.0f
#define WSCALE_INV  (1.0f/(4096.0f*4096.0f))

#define WF16_OFF 8192   // _Float16 offset into ws (floats 0..8191 spare); 16B-aligned

// ---- Merged prep: ONE kernel, 256 blocks x 256 threads. Each block
// redundantly computes S0..S3 -> T1,U in LDS (validated tiled code, ~1 us,
// fully parallel across CUs), then its 256-element fragment-major W slice.
__global__ __launch_bounds__(256)
void mpo_prep(const float* __restrict__ w, _Float16* __restrict__ Wf) {
    __shared__ __align__(16) float wL[6272];
    __shared__ __align__(16) float sL[8704];   // S0@0 S1@256 S2@4352 S3@8448
    __shared__ __align__(16) float tuL[8192];  // T1@0 U@4096
    const int tid = threadIdx.x;

    // stage all 8 cores (6272 floats = 1568 float4)
    {
        const floatx4* s4 = reinterpret_cast<const floatx4*>(w);
        floatx4* d4 = reinterpret_cast<floatx4*>(wL);
        for (int i = tid; i < 1568; i += 256) d4[i] = s4[i];
    }
    __syncthreads();

    // S0 (cores 0x1 @0,64): scalar, 256 outs
    {
        int li = tid;
        int mm = li & 3, kk = (li >> 2) & 3, c = li >> 4;
        int k1 = kk >> 1, k2 = kk & 1, m1 = mm >> 1, m2 = mm & 1;
        float s = 0.f;
#pragma unroll
        for (int b = 0; b < 16; ++b)
            s += wL[b * 4 + k1 * 2 + m1] * wL[64 + b * 64 + c * 4 + k2 * 2 + m2];
        sL[li] = s;
    }
    // S1 tiled (cores 2x3 @1088,2112)
    {
        const int i0 = (tid >> 4) * 4, j0 = (tid & 15) * 4;
        const float* Ab = wL + 1088 + (i0 >> 2) * 64;
        const float* Bb = wL + 2112 + j0;
        float acc[4][4] = {};
#pragma unroll
        for (int b = 0; b < 16; ++b) {
            floatx4 ar = *reinterpret_cast<const floatx4*>(Ab + b * 4);
            floatx4 br = *reinterpret_cast<const floatx4*>(Bb + b * 64);
#pragma unroll
            for (int r = 0; r < 4; ++r)
#pragma unroll
                for (int s = 0; s < 4; ++s) acc[r][s] += ar[r] * br[s];
        }
#pragma unroll
        for (int r = 0; r < 4; ++r)
#pragma unroll
        for (int s = 0; s < 4; ++s) {
            int i = i0 + r, j = j0 + s;
            sL[256 + (i >> 2) * 256 + (j >> 2) * 16 +
               ((i >> 1) & 1) * 8 + ((j >> 1) & 1) * 4 + (i & 1) * 2 + (j & 1)] = acc[r][s];
        }
    }
    // S2 tiled (cores 4x5 @3136,4160)
    {
        const int i0 = (tid >> 4) * 4, j0 = (tid & 15) * 4;
        const float* Ab = wL + 3136 + (i0 >> 2) * 64;
        const float* Bb = wL + 4160 + j0;
        float acc[4][4] = {};
#pragma unroll
        for (int b = 0; b < 16; ++b) {
            floatx4 ar = *reinterpret_cast<const floatx4*>(Ab + b * 4);
            floatx4 br = *reinterpret_cast<const floatx4*>(Bb + b * 64);
#pragma unroll
            for (int r = 0; r < 4; ++r)
#pragma unroll
                for (int s = 0; s < 4; ++s) acc[r][s] += ar[r] * br[s];
        }
#pragma unroll
        for (int r = 0; r < 4; ++r)
#pragma unroll
        for (int s = 0; s < 4; ++s) {
            int i = i0 + r, j = j0 + s;
            sL[4352 + (i >> 2) * 256 + (j >> 2) * 16 +
               ((i >> 1) & 1) * 8 + ((j >> 1) & 1) * 4 + (i & 1) * 2 + (j & 1)] = acc[r][s];
        }
    }
    // S3 (cores 6x7 @5184,6208): scalar, 256 outs
    {
        int li = tid;
        int mm = li & 3, kk = (li >> 2) & 3, a = li >> 4;
        int k1 = kk >> 1, k2 = kk & 1, m1 = mm >> 1, m2 = mm & 1;
        float s = 0.f;
#pragma unroll
        for (int b = 0; b < 16; ++b)
            s += wL[5184 + a * 64 + b * 4 + k1 * 2 + m1] * wL[6208 + b * 4 + k2 * 2 + m2];
        sL[8448 + li] = s;
    }
    __syncthreads();

    // T1 tiled -> tuL[0:4096)
    {
        const int p0 = (tid >> 6) * 4, q0 = (tid & 63) * 4;
        float acc[4][4] = {};
#pragma unroll
        for (int a = 0; a < 16; ++a) {
            floatx4 pr = *reinterpret_cast<const floatx4*>(sL + a * 16 + p0);
            floatx4 qr = *reinterpret_cast<const floatx4*>(sL + 256 + a * 256 + q0);
#pragma unroll
            for (int r = 0; r < 4; ++r)
#pragma unroll
                for (int s = 0; s < 4; ++s) acc[r][s] += pr[r] * qr[s];
        }
#pragma unroll
        for (int r = 0; r < 4; ++r)
#pragma unroll
        for (int s = 0; s < 4; ++s) {
            int p = p0 + r, q = q0 + s;
            tuL[(q >> 4) * 256 + ((p >> 2) * 4 + ((q >> 2) & 3)) * 16 +
                (p & 3) * 4 + (q & 3)] = acc[r][s];
        }
    }
    // U tiled -> tuL[4096:8192)
    {
        const int r0 = (tid >> 2) * 4, q0 = (tid & 3) * 4;
        float acc[4][4] = {};
#pragma unroll
        for (int b = 0; b < 16; ++b) {
            floatx4 ar = *reinterpret_cast<const floatx4*>(sL + 4352 + (r0 >> 4) * 256 + b * 16 + (r0 & 15));
            floatx4 br = *reinterpret_cast<const floatx4*>(sL + 8448 + b * 16 + q0);
#pragma unroll
            for (int r = 0; r < 4; ++r)
#pragma unroll
                for (int s = 0; s < 4; ++s) acc[r][s] += ar[r] * br[s];
        }
#pragma unroll
        for (int r = 0; r < 4; ++r)
#pragma unroll
        for (int s = 0; s < 4; ++s)
            tuL[4096 + (r0 + r) * 16 + q0 + s] = acc[r][s];
    }
    __syncthreads();

    // W slice: this block's 256 elements (16 MACs each, LDS-hot)
    {
        int idx = blockIdx.x * 256 + tid;              // 65536 total
        int J4 = idx & 255, I4 = idx >> 8;             // col, k
        int I16 = I4 >> 4, kc = (I4 >> 2) & 3, k2v = I4 & 3;
        int mc = (J4 >> 2) & 3, m2v = J4 & 3;
        int J16 = J4 >> 4;
        const float* Uc = tuL + 4096 + (((kc * 4 + mc) * 4 + k2v) * 4 + m2v);
        float s = 0.f;
#pragma unroll
        for (int a = 0; a < 16; ++a)
            s += tuL[(a * 16 + I16) * 16 + J16] * Uc[a * 256];
        int nn = J4 >> 4, lr = J4 & 15, kq = I4 >> 5, gg = (I4 >> 3) & 3, jj = I4 & 7;
        Wf[(((nn * 8 + kq) * 64) + gg * 16 + lr) * 8 + jj] = (_Float16)(s * WSCALE);
    }
}

// ---- Main fused kernel: SINGLE-SET fine-grained pipeline ----
// 256 blocks x 512 threads, W (128 KB) + dk in LDS, one barrier. 8 sets of
// 16 rows/wave; per set: {cvt a <- set s; issue set s+2; nloop(a); reduce}.
// Per-set delivery (12.5K cyc) ~= per-set LDS n-loop (12.3K) -> balanced
// pipeline, no coarse fill/drain bubbles (R12's 25K-granular passes had
// ~10us of both). dk in registers (kreg) keeps the DS pipe to B-reads only.
__global__ __launch_bounds__(512, 2)
void mpo_main(const float* __restrict__ x, const _Float16* __restrict__ Wf,
              const float* __restrict__ dk, const float* __restrict__ bias,
              float* __restrict__ out) {
    extern __shared__ _Float16 Wl[];                       // 65536 halves + 256 floats
    float* dkL = reinterpret_cast<float*>(Wl + 65536);

    const int tid  = threadIdx.x;
    const int lane = tid & 63;
    const int wave = tid >> 6;        // 0..7
    const int lrow = lane & 15;
    const int g    = lane >> 4;

    const long blockbase = (long)blockIdx.x * 1024;
    // wave's rows for set s: blockbase + s*128 + wave*16 + (g*4+r)
    const float* xb = x + (blockbase + wave * 16 + lrow) * 256 + g * 8;
    const int SET_STRIDE = 128 * 256;   // floats per set (128 rows)

    half8 a[8];
    floatx4 lo[8], hi[8];

#define SB()  __builtin_amdgcn_sched_barrier(0)
#define XLD(i, xn) do { const float* p_ = (xn) + (i) * 32;              \
                     lo[i] = *reinterpret_cast<const floatx4*>(p_);     \
                     hi[i] = *reinterpret_cast<const floatx4*>(p_ + 4); } while (0)
#define XLD_ALL(xn) do { XLD(0,xn); XLD(1,xn); XLD(2,xn); XLD(3,xn); \
                         XLD(4,xn); XLD(5,xn); XLD(6,xn); XLD(7,xn); } while (0)
#define XCVT(i) do { half8 f_;                                                \
                     f_[0] = (_Float16)lo[i][0]; f_[1] = (_Float16)lo[i][1];  \
                     f_[2] = (_Float16)lo[i][2]; f_[3] = (_Float16)lo[i][3];  \
                     f_[4] = (_Float16)hi[i][0]; f_[5] = (_Float16)hi[i][1];  \
                     f_[6] = (_Float16)hi[i][2]; f_[7] = (_Float16)hi[i][3];  \
                     a[i] = f_; } while (0)
#define XCVT_ALL() do { XCVT(0); XCVT(1); XCVT(2); XCVT(3); \
                        XCVT(4); XCVT(5); XCVT(6); XCVT(7); } while (0)

    // ---- prologue: issue set0; stage W+dk; barrier (drains set0 = fill) ----
    XLD_ALL(xb);
    SB();
    {
        const floatx4* src = reinterpret_cast<const floatx4*>(Wf);
        floatx4* dst = reinterpret_cast<floatx4*>(Wl);
#pragma unroll
        for (int i = 0; i < 16; ++i)
            dst[tid + i * 512] = src[tid + i * 512];
    }
    if (tid < 256) dkL[tid] = dk[tid];
    const float bs = bias[0];
    __syncthreads();   // the only barrier

    float kreg[16];
#pragma unroll
    for (int n = 0; n < 16; ++n) kreg[n] = dkL[n * 16 + lrow];

    XCVT_ALL();                 // a <- set 0
    XLD_ALL(xb + SET_STRIDE);   // issue set 1
    SB();

    const half8* Wv = reinterpret_cast<const half8*>(Wl);

#pragma unroll 1
    for (int s = 0; s < 8; ++s) {
        float rp[4] = {0, 0, 0, 0};
#pragma unroll 1
        for (int n = 0; n < 16; ++n) {
            const half8* Wn = Wv + n * 512 + lane;
            floatx4 c0 = {0, 0, 0, 0};
#pragma unroll
            for (int kk = 0; kk < 8; ++kk)
                c0 = __builtin_amdgcn_mfma_f32_16x16x32_f16(a[kk], Wn[kk * 64], c0, 0, 0, 0);
            const float kv = kreg[n];
#pragma unroll
            for (int r = 0; r < 4; ++r)
                rp[r] += c0[r] * c0[r] * kv;
        }

        // rotate the pipeline: a <- set s+1 (small stall), issue set s+2
        if (s < 7) { XCVT_ALL(); }
        if (s < 6) { XLD_ALL(xb + (s + 2) * SET_STRIDE); }
        SB();

        // reduce over the 16 cols (lanes sharing g) and store this set
#pragma unroll
        for (int r = 0; r < 4; ++r) {
            float v = rp[r];
            v += __shfl_xor(v, 1);
            v += __shfl_xor(v, 2);
            v += __shfl_xor(v, 4);
            v += __shfl_xor(v, 8);
            rp[r] = v;
        }
        if (lrow == 0) {
            floatx4 o;
#pragma unroll
            for (int r = 0; r < 4; ++r) o[r] = rp[r] * WSCALE_INV + bs;
            *reinterpret_cast<floatx4*>(out + blockbase + s * 128 + wave * 16 + g * 4) = o;
        }
        SB();
    }
}

extern "C" void kernel_launch(void* const* d_in, const int* in_sizes, int n_in,
                              void* d_out, int out_size, void* d_ws, size_t ws_size,
                              hipStream_t stream) {
    const float* x    = (const float*)d_in[0];
    const float* w    = (const float*)d_in[1];
    const float* dk   = (const float*)d_in[2];
    const float* bias = (const float*)d_in[3];
    float* out = (float*)d_out;
    float* ws  = (float*)d_ws;

    _Float16* Wf16 = (_Float16*)(ws + WF16_OFF);

    // Allow 129 KB dynamic LDS for mpo_main (host-side attr; validated R5-R12).
    static bool attr_set = false;
    if (!attr_set) {
        hipFuncSetAttribute((const void*)mpo_main,
                            hipFuncAttributeMaxDynamicSharedMemorySize, 132096);
        attr_set = true;
    }

    // W contraction: ONE kernel (per-block redundant T1/U + W slice)
    mpo_prep<<<256, 256, 0, stream>>>(w, Wf16);

    // Main fused GEMM + square + dot: 256 blocks x 512 threads, 129 KB LDS
    mpo_main<<<256, 512, 132096, stream>>>(x, Wf16, dk, bias, out);
}